// Round 7
// baseline (377.255 us; speedup 1.0000x reference)
//
#include <hip/hip_runtime.h>

typedef unsigned short u16;
typedef __attribute__((ext_vector_type(4))) unsigned short u16x4;
typedef __attribute__((ext_vector_type(8))) unsigned short u16x8;
typedef __attribute__((ext_vector_type(8))) __bf16 bf16x8;
typedef __attribute__((ext_vector_type(4))) float f32x4;

#define SLEN_ 2048
#define BSZ_ 8
#define NH_ 16
#define DH_ 64
#define IND_ 1024
#define MROWS_ (SLEN_*BSZ_)   // 16384
#define NQKV_ (NH_*3*DH_)     // 3072
#define NOUT_ (NH_*DH_)       // 1024
#define NT_ 16                // K-tiles of 64 (K=1024)

__device__ __forceinline__ float b2f(u16 u) {
    return __uint_as_float(((unsigned)u) << 16);
}
__device__ __forceinline__ u16 f2b(float f) {
    unsigned u = __float_as_uint(f);
    u = u + 0x7FFFu + ((u >> 16) & 1u);   // RNE
    return (u16)(u >> 16);
}

#define GLOAD_LDS16(g, l) __builtin_amdgcn_global_load_lds( \
    (const __attribute__((address_space(1))) unsigned int*)(g), \
    (__attribute__((address_space(3))) unsigned int*)(l), 16, 0, 0)

// swizzled LDS byte offset for [64][64] bf16 tiles (row stride 128 B)
#define TI(r, c) ((((r) << 7) + ((c) << 1)) ^ (((r) & 7) << 4))

// ---------------- cast fp32 weights -> bf16 ----------------
__global__ __launch_bounds__(256) void cast_weights(
        const float* __restrict__ wq, const float* __restrict__ wo,
        u16* __restrict__ wqb, u16* __restrict__ wob)
{
    int i = blockIdx.x * 256 + threadIdx.x;
    const int NQ4 = NQKV_ * IND_ / 4;
    float4 v;
    u16* dst;
    if (i < NQ4) { v = ((const float4*)wq)[i]; dst = wqb + (size_t)i * 4; }
    else { int j = i - NQ4; v = ((const float4*)wo)[j]; dst = wob + (size_t)j * 4; }
    u16x4 o;
    o[0] = f2b(v.x); o[1] = f2b(v.y); o[2] = f2b(v.z); o[3] = f2b(v.w);
    *(u16x4*)dst = o;
}

// ---------------- LayerNorm -> bf16 ----------------
__global__ __launch_bounds__(256) void ln_kernel(
        const float* __restrict__ x, const float* __restrict__ g,
        const float* __restrict__ bt, u16* __restrict__ h)
{
    int row = blockIdx.x, tid = threadIdx.x;
    const float4 v = ((const float4*)(x + (size_t)row * IND_))[tid];
    float s  = v.x + v.y + v.z + v.w;
    float s2 = v.x*v.x + v.y*v.y + v.z*v.z + v.w*v.w;
    #pragma unroll
    for (int m = 1; m < 64; m <<= 1) { s += __shfl_xor(s, m); s2 += __shfl_xor(s2, m); }
    __shared__ float sh[8];
    int w = tid >> 6, l = tid & 63;
    if (l == 0) { sh[w] = s; sh[4 + w] = s2; }
    __syncthreads();
    s  = sh[0] + sh[1] + sh[2] + sh[3];
    s2 = sh[4] + sh[5] + sh[6] + sh[7];
    float mu   = s * (1.f / IND_);
    float var  = s2 * (1.f / IND_) - mu * mu;
    float rstd = rsqrtf(var + 1e-5f);
    float4 gg = ((const float4*)g)[tid];
    float4 bb = ((const float4*)bt)[tid];
    u16x4 o;
    o[0] = f2b((v.x - mu) * rstd * gg.x + bb.x);
    o[1] = f2b((v.y - mu) * rstd * gg.y + bb.y);
    o[2] = f2b((v.z - mu) * rstd * gg.z + bb.z);
    o[3] = f2b((v.w - mu) * rstd * gg.w + bb.w);
    ((u16x4*)(h + (size_t)row * IND_))[tid] = o;
}

// ---------------- 256x256 bf16 GEMM, C[M,N] = A[M,K]*B[N,K]^T, BK=64 ----------------
// B-DIRECT variant: B-frags read straight from global (L2-resident via locality
// map; each B row is wave-private -> zero duplication), A through 64KB dbuf LDS.
// ONE sync per K-tile (vmcnt(0)+barrier guarding the A-buffer swap -- the only
// dependency the compiler can't see: global_load_lds -> ds_read). No manual
// lgkm/sched_barrier/setprio: the tile body is one barrier-free region, so the
// compiler freely interleaves 16 ds_read_b128 + 8 B-gloads + 4 gload_lds with
// 64 MFMAs (m97 mechanism, at 4:1 MFMA:ds-read). B prefetched one tile ahead.
template<int MODE>
__global__ __launch_bounds__(512, 2) void gemm256(
        const u16* __restrict__ A, const u16* __restrict__ Bm,
        u16* __restrict__ Cb, float* __restrict__ Cf, const float* __restrict__ X,
        int M, int N, int K)
{
    __shared__ char smem[65536];   // A only: 2 bufs x 32KB

    const int tid = threadIdx.x;
    const int w = tid >> 6, l = tid & 63;
    const int wmi = w >> 2, wni = w & 3;
    const int fr = l & 15, fq = l >> 4;

    // locality-aware XCD block map (gridDim.x == 64 required)
    const int h = blockIdx.y * gridDim.x + blockIdx.x;
    const int xcd = h & 7, i = h >> 3;
    const int bm = xcd * 8 + (i & 7);
    const int bn = i >> 3;

    // ---- A staging: wave w, load j covers tile rows [j*64 + w*8, +8)
    const int sr = l >> 3;
    const int sc = ((l & 7) ^ sr) * 8;           // inverse-swizzled source col
    const u16* ga = A + (size_t)(bm * 256 + w * 8 + sr) * K + sc;
    char* lA = smem + w * 1024;
    const size_t K64 = (size_t)K * 64;

#define STAGEA(tt, bufb) { \
    const u16* gat = ga + (tt) * 64; \
    char* la = lA + (bufb) * 32768; \
    GLOAD_LDS16(gat,            la);            \
    GLOAD_LDS16(gat + K64,      la + 8192);     \
    GLOAD_LDS16(gat + 2 * K64,  la + 16384);    \
    GLOAD_LDS16(gat + 3 * K64,  la + 24576);    \
}

    // ---- B direct-load pointers (wave-private rows; 16B/lane)
    const u16* gB[4];
    #pragma unroll
    for (int n = 0; n < 4; n++)
        gB[n] = Bm + (size_t)(bn * 256 + wni * 64 + n * 16 + fr) * K + fq * 8;

    // ---- A read bases (swizzled)
    const int cswz = (fr & 7) << 4;
    const int c0 = (fq * 16) ^ cswz;             // ks0 byte col
    const int c1 = (64 + fq * 16) ^ cswz;        // ks1 byte col
    const char* rdA = smem + (wmi * 128 + fr) * 128;

    f32x4 acc[8][4] = {};
    bf16x8 B0[4][2], B1[4][2];

#define LOADB(dst, tt) { \
    _Pragma("unroll") for (int n_ = 0; n_ < 4; n_++) \
        _Pragma("unroll") for (int ks_ = 0; ks_ < 2; ks_++) \
            dst[n_][ks_] = *(const bf16x8*)(gB[n_] + (tt) * 64 + ks_ * 32); \
}

#define TILE(tt, bufb, Bc, Bn) { \
    if ((tt) + 1 < NT_) { \
        STAGEA((tt) + 1, ((tt) + 1) & 1); \
        LOADB(Bn, (tt) + 1); \
    } \
    const char* bA = rdA + (bufb) * 32768; \
    _Pragma("unroll") for (int ks_ = 0; ks_ < 2; ks_++) { \
        _Pragma("unroll") for (int mh_ = 0; mh_ < 2; mh_++) { \
            bf16x8 Af_[4]; \
            _Pragma("unroll") for (int mm = 0; mm < 4; mm++) \
                Af_[mm] = *(const bf16x8*)(bA + (mh_ * 4 + mm) * 2048 + (ks_ ? c1 : c0)); \
            _Pragma("unroll") for (int mm = 0; mm < 4; mm++) \
                _Pragma("unroll") for (int nn = 0; nn < 4; nn++) \
                    acc[mh_ * 4 + mm][nn] = __builtin_amdgcn_mfma_f32_16x16x32_bf16( \
                        Af_[mm], Bc[nn][ks_], acc[mh_ * 4 + mm][nn], 0, 0, 0); \
        } \
    } \
    asm volatile("s_waitcnt vmcnt(0)" ::: "memory"); \
    __builtin_amdgcn_s_barrier(); \
}

    // prologue: tile 0 -> buf0 + B0
    STAGEA(0, 0);
    LOADB(B0, 0);
    asm volatile("s_waitcnt vmcnt(0)" ::: "memory");
    __builtin_amdgcn_s_barrier();

    #pragma unroll 1
    for (int t = 0; t < NT_; t += 2) {
        TILE(t,     0, B0, B1);
        TILE(t + 1, 1, B1, B0);
    }
#undef TILE
#undef LOADB
#undef STAGEA

    // epilogue: (m, r, n) order -> 4 consecutive 32B chunks per row per wave
    #pragma unroll
    for (int m = 0; m < 8; m++)
        #pragma unroll
        for (int r = 0; r < 4; r++) {
            int row = bm * 256 + wmi * 128 + m * 16 + fq * 4 + r;
            #pragma unroll
            for (int n = 0; n < 4; n++) {
                int col = bn * 256 + wni * 64 + n * 16 + fr;
                float vv = acc[m][n][r];
                if (MODE == 0) {
                    Cb[(size_t)row * N + col] = f2b(vv);
                } else {
                    size_t idx = (size_t)row * N + col;
                    Cf[idx] = vv + X[idx];
                }
            }
        }
}

// ---------------- scanA: per-chunk parallel (grid 4096 = n*128 + bh) ----------------
// P = tril(K·Q^T); O_intra = P·V -> obf; S_c[d][e] = sum_t K[t][d]V[t][e] -> Sbuf bf16
__global__ __launch_bounds__(256) void scanA(
        const u16* __restrict__ qkv, u16* __restrict__ obf, u16* __restrict__ Sbuf)
{
    __shared__ u16 Q_l[4096], K_l[4096], Kt_l[4096], Vt_l[4096], P_l[4096];

    const int blk = blockIdx.x;
    const int bh = blk & 127, n = blk >> 7;
    const int b = bh >> 4, hh = bh & 15;
    const int tid = threadIdx.x;
    const int w = tid >> 6, l = tid & 63;
    const int fr = l & 15, fq = l >> 4;

    int goff = (w == 0) ? 0 : (w == 1) ? 64 : (w == 2) ? 128 : 160;
    const u16* g0 = qkv + ((size_t)(n * 64 + l) * BSZ_ + b) * NQKV_ + hh * 192 + goff;

    u16x8 pre[8];
    if (w < 2) {
        #pragma unroll
        for (int j = 0; j < 8; j++) pre[j] = *(const u16x8*)(g0 + j * 8);
    } else {
        #pragma unroll
        for (int j = 0; j < 4; j++) pre[j] = *(const u16x8*)(g0 + j * 8);
    }

    if (w < 2) {
        float f[64];
        #pragma unroll
        for (int j = 0; j < 8; j++)
            #pragma unroll
            for (int m = 0; m < 8; m++) {
                float x = b2f(pre[j][m]);
                f[j * 8 + m] = x > 0.f ? x + 1.f : __expf(x);
            }
        float s = 0.f;
        #pragma unroll
        for (int i = 0; i < 64; i++) s += f[i];
        float inv = 1.f / (s + 1e-5f);
        u16* dst = (w == 0) ? Q_l : K_l;
        #pragma unroll
        for (int j = 0; j < 8; j++) {
            u16x8 o;
            #pragma unroll
            for (int m = 0; m < 8; m++) o[m] = f2b(f[j * 8 + m] * inv);
            *(u16x8*)((char*)dst + TI(l, j * 8)) = o;
            if (w == 1) {
                #pragma unroll
                for (int m = 0; m < 8; m++)
                    *(u16*)((char*)Kt_l + TI(j * 8 + m, l)) = o[m];
            }
        }
    } else {
        int e0 = (w == 2) ? 0 : 32;
        #pragma unroll
        for (int j = 0; j < 4; j++)
            #pragma unroll
            for (int m = 0; m < 8; m++)
                *(u16*)((char*)Vt_l + TI(e0 + j * 8 + m, l)) = pre[j][m];
    }
    __syncthreads();

    f32x4 aS[4] = {};
    bf16x8 aK[2];
    #pragma unroll
    for (int ks = 0; ks < 2; ks++)
        aK[ks] = *(const bf16x8*)((const char*)K_l + TI(w * 16 + fr, ks * 32 + fq * 8));
    #pragma unroll
    for (int jt = 0; jt < 4; jt++)
        #pragma unroll
        for (int ks = 0; ks < 2; ks++) {
            bf16x8 bq = *(const bf16x8*)((const char*)Q_l + TI(jt * 16 + fr, ks * 32 + fq * 8));
            aS[jt] = __builtin_amdgcn_mfma_f32_16x16x32_bf16(aK[ks], bq, aS[jt], 0, 0, 0);
        }
    #pragma unroll
    for (int jt = 0; jt < 4; jt++) {
        int t = jt * 16 + fr;
        int s0 = w * 16 + fq * 4;
        u16 e0 = (s0 + 0 <= t) ? f2b(aS[jt][0]) : (u16)0;
        u16 e1 = (s0 + 1 <= t) ? f2b(aS[jt][1]) : (u16)0;
        u16 e2 = (s0 + 2 <= t) ? f2b(aS[jt][2]) : (u16)0;
        u16 e3 = (s0 + 3 <= t) ? f2b(aS[jt][3]) : (u16)0;
        uint2 pkk;
        pkk.x = (unsigned)e0 | ((unsigned)e1 << 16);
        pkk.y = (unsigned)e2 | ((unsigned)e3 << 16);
        *(uint2*)((char*)P_l + TI(t, s0)) = pkk;
    }
    __syncthreads();

    f32x4 aO[4] = {}, aS2[4] = {};
    bf16x8 ap[2], akt[2];
    #pragma unroll
    for (int ks = 0; ks < 2; ks++) {
        ap[ks]  = *(const bf16x8*)((const char*)P_l  + TI(w * 16 + fr, ks * 32 + fq * 8));
        akt[ks] = *(const bf16x8*)((const char*)Kt_l + TI(w * 16 + fr, ks * 32 + fq * 8));
    }
    #pragma unroll
    for (int jt = 0; jt < 4; jt++) {
        #pragma unroll
        for (int ks = 0; ks < 2; ks++) {
            bf16x8 bv = *(const bf16x8*)((const char*)Vt_l + TI(jt * 16 + fr, ks * 32 + fq * 8));
            aO[jt]  = __builtin_amdgcn_mfma_f32_16x16x32_bf16(ap[ks],  bv, aO[jt],  0, 0, 0);
            aS2[jt] = __builtin_amdgcn_mfma_f32_16x16x32_bf16(akt[ks], bv, aS2[jt], 0, 0, 0);
        }
    }
    __syncthreads();

    u16* Sg = Sbuf + ((size_t)bh * 32 + n) * 4096;
    #pragma unroll
    for (int jt = 0; jt < 4; jt++)
        #pragma unroll
        for (int r = 0; r < 4; r++) {
            int rr = w * 16 + fq * 4 + r, cc = jt * 16 + fr;
            *(u16*)((char*)P_l + TI(rr, cc)) = f2b(aO[jt][r]);   // rr=t, cc=e
            Sg[rr * 64 + cc] = f2b(aS2[jt][r]);                  // rr=d, cc=e
        }
    __syncthreads();

    {
        int t = tid >> 2, seg = tid & 3;
        u16x8 o1 = *(const u16x8*)((const char*)P_l + TI(t, seg * 16));
        u16x8 o2 = *(const u16x8*)((const char*)P_l + TI(t, seg * 16 + 8));
        u16* gd = obf + ((size_t)(n * 64 + t) * BSZ_ + b) * NOUT_ + hh * 64 + seg * 16;
        *(u16x8*)(gd) = o1;
        *(u16x8*)(gd + 8) = o2;
    }
}

// ---------------- scanB: exclusive prefix over chunks (in-place bf16) ----------------
__global__ __launch_bounds__(256) void scanB(
        u16* __restrict__ Sbuf, const float* __restrict__ state, float* __restrict__ wfin)
{
    const int blk = blockIdx.x;
    const int bh = blk >> 2;
    const int e0 = (blk & 3) * 1024 + threadIdx.x * 4;
    float4 acc = *(const float4*)(state + (size_t)bh * 4096 + e0);
    u16* Sp = Sbuf + (size_t)bh * 32 * 4096 + e0;
    #pragma unroll
    for (int nn = 0; nn < 32; nn++) {
        u16x4 s = *(const u16x4*)(Sp + nn * 4096);
        u16x4 p;
        p[0] = f2b(acc.x); p[1] = f2b(acc.y); p[2] = f2b(acc.z); p[3] = f2b(acc.w);
        *(u16x4*)(Sp + nn * 4096) = p;
        acc.x += b2f(s[0]); acc.y += b2f(s[1]);
        acc.z += b2f(s[2]); acc.w += b2f(s[3]);
    }
    *(float4*)(wfin + (size_t)bh * 4096 + e0) = acc;
}

// ---------------- scanC: O += Q·W_prefix (grid 4096 = n*128 + bh) ----------------
__global__ __launch_bounds__(256) void scanC(
        const u16* __restrict__ qkv, const u16* __restrict__ Sbuf, u16* __restrict__ obf)
{
    __shared__ u16 Q_l[4096], W_l[4096];

    const int blk = blockIdx.x;
    const int bh = blk & 127, n = blk >> 7;
    const int b = bh >> 4, hh = bh & 15;
    const int tid = threadIdx.x;
    const int w = tid >> 6, l = tid & 63;
    const int fr = l & 15, fq = l >> 4;

    const u16* g0 = qkv + ((size_t)(n * 64 + l) * BSZ_ + b) * NQKV_ + hh * 192;
    u16x8 pre[8];
    if (w == 0) {
        #pragma unroll
        for (int j = 0; j < 8; j++) pre[j] = *(const u16x8*)(g0 + j * 8);
    }

    const u16* Wp = Sbuf + ((size_t)bh * 32 + n) * 4096;
    #pragma unroll
    for (int k2 = 0; k2 < 4; k2++) {
        int g = tid * 4 + k2 * 1024;
        u16x4 s = *(const u16x4*)(Wp + g);
        int d = g >> 6, e = g & 63;
        #pragma unroll
        for (int i2 = 0; i2 < 4; i2++)
            *(u16*)((char*)W_l + TI(e + i2, d)) = s[i2];
    }

    if (w == 0) {
        float f[64];
        #pragma unroll
        for (int j = 0; j < 8; j++)
            #pragma unroll
            for (int m = 0; m < 8; m++) {
                float x = b2f(pre[j][m]);
                f[j * 8 + m] = x > 0.f ? x + 1.f : __expf(x);
            }
        float s = 0.f;
        #pragma unroll
        for (int i = 0; i < 64; i++) s += f[i];
        float inv = 1.f / (s + 1e-5f);
        #pragma unroll
        for (int j = 0; j < 8; j++) {
            u16x8 o;
            #pragma unroll
            for (int m = 0; m < 8; m++) o[m] = f2b(f[j * 8 + m] * inv);
            *(u16x8*)((char*)Q_l + TI(l, j * 8)) = o;
        }
    }
    __syncthreads();

    f32x4 aO[4] = {};
    bf16x8 aq[2];
    #pragma unroll
    for (int ks = 0; ks < 2; ks++)
        aq[ks] = *(const bf16x8*)((const char*)Q_l + TI(w * 16 + fr, ks * 32 + fq * 8));
    #pragma unroll
    for (int jt = 0; jt < 4; jt++)
        #pragma unroll
        for (int ks = 0; ks < 2; ks++) {
            bf16x8 bw = *(const bf16x8*)((const char*)W_l + TI(jt * 16 + fr, ks * 32 + fq * 8));
            aO[jt] = __builtin_amdgcn_mfma_f32_16x16x32_bf16(aq[ks], bw, aO[jt], 0, 0, 0);
        }
    __syncthreads();

    #pragma unroll
    for (int jt = 0; jt < 4; jt++)
        #pragma unroll
        for (int r = 0; r < 4; r++)
            *(u16*)((char*)W_l + TI(w * 16 + fq * 4 + r, jt * 16 + fr)) = f2b(aO[jt][r]);
    __syncthreads();

    {
        int t = tid >> 2, seg = tid & 3;
        u16* gd = obf + ((size_t)(n * 64 + t) * BSZ_ + b) * NOUT_ + hh * 64 + seg * 16;
        u16x8 a1 = *(const u16x8*)((const char*)W_l + TI(t, seg * 16));
        u16x8 a2 = *(const u16x8*)((const char*)W_l + TI(t, seg * 16 + 8));
        u16x8 g1 = *(const u16x8*)(gd);
        u16x8 g2 = *(const u16x8*)(gd + 8);
        u16x8 r1, r2;
        #pragma unroll
        for (int m = 0; m < 8; m++) {
            r1[m] = f2b(b2f(a1[m]) + b2f(g1[m]));
            r2[m] = f2b(b2f(a2[m]) + b2f(g2[m]));
        }
        *(u16x8*)(gd) = r1;
        *(u16x8*)(gd + 8) = r2;
    }
}

extern "C" void kernel_launch(void* const* d_in, const int* in_sizes, int n_in,
                              void* d_out, int out_size, void* d_ws, size_t ws_size,
                              hipStream_t stream) {
    const float* x     = (const float*)d_in[0];
    const float* state = (const float*)d_in[1];
    const float* wqkv  = (const float*)d_in[2];
    const float* wout  = (const float*)d_in[3];
    const float* gamma = (const float*)d_in[4];
    const float* beta  = (const float*)d_in[5];

    float* out0 = (float*)d_out;
    float* wfin = (float*)d_out + (size_t)MROWS_ * IND_;

    char* ws = (char*)d_ws;
    u16* qkv_bf = (u16*)ws;                                   // 96 MiB
    u16* h_bf   = (u16*)(ws + 100663296);                     // 32 MiB (o_bf reuse)
    u16* o_bf   = h_bf;
    u16* wq_bf  = (u16*)(ws + 134217728);                     // 6 MiB
    u16* wo_bf  = (u16*)(ws + 140509184);                     // 2 MiB
    u16* S_bf   = (u16*)(ws + 142606336);                     // 32 MiB (S / prefix)

    cast_weights<<<4096, 256, 0, stream>>>(wqkv, wout, wq_bf, wo_bf);
    ln_kernel<<<MROWS_, 256, 0, stream>>>(x, gamma, beta, h_bf);
    dim3 g1(MROWS_ / 256, NQKV_ / 256);   // 64 x 12 = 768 blocks
    gemm256<0><<<g1, 512, 0, stream>>>(h_bf, wq_bf, qkv_bf, nullptr, nullptr, MROWS_, NQKV_, IND_);
    scanA<<<4096, 256, 0, stream>>>(qkv_bf, o_bf, S_bf);
    scanB<<<512, 256, 0, stream>>>(S_bf, state, wfin);
    scanC<<<4096, 256, 0, stream>>>(qkv_bf, S_bf, o_bf);
    dim3 g2(MROWS_ / 256, NOUT_ / 256);   // 64 x 4 = 256 blocks
    gemm256<1><<<g2, 512, 0, stream>>>(o_bf, wo_bf, nullptr, out0, x, MROWS_, NOUT_, IND_);
}

// Round 8
// 263.938 us; speedup vs baseline: 1.4293x; 1.4293x over previous
//
#include <hip/hip_runtime.h>

typedef unsigned short u16;
typedef __attribute__((ext_vector_type(4))) unsigned short u16x4;
typedef __attribute__((ext_vector_type(8))) unsigned short u16x8;
typedef __attribute__((ext_vector_type(8))) __bf16 bf16x8;
typedef __attribute__((ext_vector_type(4))) float f32x4;

#define SLEN_ 2048
#define BSZ_ 8
#define NH_ 16
#define DH_ 64
#define IND_ 1024
#define MROWS_ (SLEN_*BSZ_)   // 16384
#define NQKV_ (NH_*3*DH_)     // 3072
#define NOUT_ (NH_*DH_)       // 1024
#define NT_ 16                // K-tiles of 64 (K=1024)

__device__ __forceinline__ float b2f(u16 u) {
    return __uint_as_float(((unsigned)u) << 16);
}
__device__ __forceinline__ u16 f2b(float f) {
    unsigned u = __float_as_uint(f);
    u = u + 0x7FFFu + ((u >> 16) & 1u);   // RNE
    return (u16)(u >> 16);
}

#define GLOAD_LDS16(g, l) __builtin_amdgcn_global_load_lds( \
    (const __attribute__((address_space(1))) unsigned int*)(g), \
    (__attribute__((address_space(3))) unsigned int*)(l), 16, 0, 0)

// swizzled LDS byte offset for [64][64] bf16 tiles (row stride 128 B) -- scans
#define TI(r, c) ((((r) << 7) + ((c) << 1)) ^ (((r) & 7) << 4))

// ---------------- cast fp32 weights -> bf16 ----------------
__global__ __launch_bounds__(256) void cast_weights(
        const float* __restrict__ wq, const float* __restrict__ wo,
        u16* __restrict__ wqb, u16* __restrict__ wob)
{
    int i = blockIdx.x * 256 + threadIdx.x;
    const int NQ4 = NQKV_ * IND_ / 4;
    float4 v;
    u16* dst;
    if (i < NQ4) { v = ((const float4*)wq)[i]; dst = wqb + (size_t)i * 4; }
    else { int j = i - NQ4; v = ((const float4*)wo)[j]; dst = wob + (size_t)j * 4; }
    u16x4 o;
    o[0] = f2b(v.x); o[1] = f2b(v.y); o[2] = f2b(v.z); o[3] = f2b(v.w);
    *(u16x4*)dst = o;
}

// ---------------- LayerNorm -> bf16 ----------------
__global__ __launch_bounds__(256) void ln_kernel(
        const float* __restrict__ x, const float* __restrict__ g,
        const float* __restrict__ bt, u16* __restrict__ h)
{
    int row = blockIdx.x, tid = threadIdx.x;
    const float4 v = ((const float4*)(x + (size_t)row * IND_))[tid];
    float s  = v.x + v.y + v.z + v.w;
    float s2 = v.x*v.x + v.y*v.y + v.z*v.z + v.w*v.w;
    #pragma unroll
    for (int m = 1; m < 64; m <<= 1) { s += __shfl_xor(s, m); s2 += __shfl_xor(s2, m); }
    __shared__ float sh[8];
    int w = tid >> 6, l = tid & 63;
    if (l == 0) { sh[w] = s; sh[4 + w] = s2; }
    __syncthreads();
    s  = sh[0] + sh[1] + sh[2] + sh[3];
    s2 = sh[4] + sh[5] + sh[6] + sh[7];
    float mu   = s * (1.f / IND_);
    float var  = s2 * (1.f / IND_) - mu * mu;
    float rstd = rsqrtf(var + 1e-5f);
    float4 gg = ((const float4*)g)[tid];
    float4 bb = ((const float4*)bt)[tid];
    u16x4 o;
    o[0] = f2b((v.x - mu) * rstd * gg.x + bb.x);
    o[1] = f2b((v.y - mu) * rstd * gg.y + bb.y);
    o[2] = f2b((v.z - mu) * rstd * gg.z + bb.z);
    o[3] = f2b((v.w - mu) * rstd * gg.w + bb.w);
    ((u16x4*)(h + (size_t)row * IND_))[tid] = o;
}

// ---------------- 256x256 bf16 GEMM, C[M,N] = A[M,K]*B[N,K]^T, BK=64 ----------------
// Counted-vmcnt 4-phase schedule (T3+T4):
//   LDS: 2 dbuf x { A:[kh][256][32], B:[kh][256][32] } = 128 KB; regions 16KB,
//   64B rows, swizzle byte ^= ((row&3)<<4), inverse-swizzled global source.
//   Phase q=(kh=q>>1, mh=q&1): {stage ONE 16KB region of tile t+1 (2 gload_lds);
//   8/4 ds_read_b128; barrier; lgkm(0)+sched_barrier; setprio(1); 16 MFMA;
//   setprio(0); vmcnt(4); barrier}.  vmcnt(4) leaves the newest 2 stage-events
//   in flight -- NEVER drains to 0 in the loop (m218 mechanism). Ledger:
//   q0 stages A[kh0](t+1) (needed end-q3: 4 phases), q1 B[kh0] (3), q2 A[kh1]
//   (forced by end-q0' vmcnt), q3 B[kh1] (forced by end-q1'). WAR: stages hit
//   buf[(t+1)&1], last read at tile t-1, all waves past its final barrier.
template<int MODE>
__global__ __launch_bounds__(512, 2) void gemm256(
        const u16* __restrict__ A, const u16* __restrict__ Bm,
        u16* __restrict__ Cb, float* __restrict__ Cf, const float* __restrict__ X,
        int M, int N, int K)
{
    __shared__ char smem[131072];   // [buf][A kh0|A kh1|B kh0|B kh1] x 16KB

    const int tid = threadIdx.x;
    const int w = tid >> 6, l = tid & 63;
    const int wmi = w >> 2, wni = w & 3;
    const int fr = l & 15, fq = l >> 4;

    // locality-aware XCD block map (gridDim.x == 64 required)
    const int h = blockIdx.y * gridDim.x + blockIdx.x;
    const int xcd = h & 7, i = h >> 3;
    const int bm = xcd * 8 + (i & 7);
    const int bn = i >> 3;

    // ---- staging bases: region row = tid>>2 (and +128), slot = tid&3,
    //      source col pre-inverse-swizzled: (slot ^ (row&3))*8
    const int srow = tid >> 2;
    const int sslot = ((tid & 3) ^ (srow & 3)) * 8;
    const u16* gaS = A  + (size_t)(bm * 256 + srow) * K + sslot;
    const u16* gbS = Bm + (size_t)(bn * 256 + srow) * K + sslot;
    const size_t K128 = (size_t)K * 128;

    // STAGE one region: matrix sel (0=A,1=B), kh, tile tt
#define STAGE_EV(sel, kh, tt) { \
    const u16* gs = ((sel) ? gbS : gaS) + (tt) * 64 + (kh) * 32; \
    char* ld = smem + (((tt) & 1) * 65536) + ((sel) * 32768) + ((kh) * 16384) + tid * 16; \
    GLOAD_LDS16(gs,         ld); \
    GLOAD_LDS16(gs + K128,  ld + 8192); \
}

    // ---- read offsets (within a [256][32] region; 64B rows, swizzled)
    const int cswz = ((fq ^ (fr & 3)) << 4);
    const int rdAo = (wmi * 128 + fr) * 64 + cswz;           // + (mh*4+mm)*1024
    const int rdBo = (wni * 64 + fr) * 64 + cswz;            // + nn*1024

    f32x4 acc[8][4] = {};
    bf16x8 Bf[4];   // persists across the two mh phases of a kh

#define PHASE(kh, mh, SSEL, SKH, DOREADB) { \
        if (t + 1 < NT_) STAGE_EV(SSEL, SKH, t + 1); \
        const char* base = smem + cur + (kh) * 16384; \
        bf16x8 Af_[4]; \
        _Pragma("unroll") for (int mm = 0; mm < 4; mm++) \
            Af_[mm] = *(const bf16x8*)(base + rdAo + ((mh) * 4 + mm) * 1024); \
        if (DOREADB) { \
            _Pragma("unroll") for (int nn = 0; nn < 4; nn++) \
                Bf[nn] = *(const bf16x8*)(base + 32768 + rdBo + nn * 1024); \
        } \
        __builtin_amdgcn_s_barrier(); \
        asm volatile("s_waitcnt lgkmcnt(0)" ::: "memory"); \
        __builtin_amdgcn_sched_barrier(0); \
        __builtin_amdgcn_s_setprio(1); \
        _Pragma("unroll") for (int mm = 0; mm < 4; mm++) \
            _Pragma("unroll") for (int nn = 0; nn < 4; nn++) \
                acc[(mh) * 4 + mm][nn] = __builtin_amdgcn_mfma_f32_16x16x32_bf16( \
                    Af_[mm], Bf[nn], acc[(mh) * 4 + mm][nn], 0, 0, 0); \
        __builtin_amdgcn_s_setprio(0); \
        asm volatile("s_waitcnt vmcnt(4)" ::: "memory"); \
        __builtin_amdgcn_s_barrier(); \
}

    // ---- prologue: stage tile 0 fully (4 events), drain once
    STAGE_EV(0, 0, 0); STAGE_EV(1, 0, 0); STAGE_EV(0, 1, 0); STAGE_EV(1, 1, 0);
    asm volatile("s_waitcnt vmcnt(0)" ::: "memory");
    __builtin_amdgcn_s_barrier();

    #pragma unroll 1
    for (int t = 0; t < NT_; t++) {
        const int cur = (t & 1) * 65536;
        PHASE(0, 0, 0, 0, 1)   // q0: kh0/mh0, read B(kh0), stage A[kh0](t+1)
        PHASE(0, 1, 1, 0, 0)   // q1: kh0/mh1,               stage B[kh0](t+1)
        PHASE(1, 0, 0, 1, 1)   // q2: kh1/mh0, read B(kh1), stage A[kh1](t+1)
        PHASE(1, 1, 1, 1, 0)   // q3: kh1/mh1,               stage B[kh1](t+1)
    }
#undef PHASE
#undef STAGE_EV
    // epilogue drain (t+... nothing outstanding needed; stores below are global)
    asm volatile("s_waitcnt vmcnt(0)" ::: "memory");

    // ---- epilogue: (m, r, n) order -> 4 consecutive 32B chunks per row per wave
    #pragma unroll
    for (int m = 0; m < 8; m++)
        #pragma unroll
        for (int r = 0; r < 4; r++) {
            int row = bm * 256 + wmi * 128 + m * 16 + fq * 4 + r;
            #pragma unroll
            for (int n = 0; n < 4; n++) {
                int col = bn * 256 + wni * 64 + n * 16 + fr;
                float vv = acc[m][n][r];
                if (MODE == 0) {
                    Cb[(size_t)row * N + col] = f2b(vv);
                } else {
                    size_t idx = (size_t)row * N + col;
                    Cf[idx] = vv + X[idx];
                }
            }
        }
}

// ---------------- scanA: per-chunk parallel (grid 4096 = n*128 + bh) ----------------
// P = tril(K·Q^T); O_intra = P·V -> obf; S_c[d][e] = sum_t K[t][d]V[t][e] -> Sbuf bf16
__global__ __launch_bounds__(256) void scanA(
        const u16* __restrict__ qkv, u16* __restrict__ obf, u16* __restrict__ Sbuf)
{
    __shared__ u16 Q_l[4096], K_l[4096], Kt_l[4096], Vt_l[4096], P_l[4096];

    const int blk = blockIdx.x;
    const int bh = blk & 127, n = blk >> 7;
    const int b = bh >> 4, hh = bh & 15;
    const int tid = threadIdx.x;
    const int w = tid >> 6, l = tid & 63;
    const int fr = l & 15, fq = l >> 4;

    int goff = (w == 0) ? 0 : (w == 1) ? 64 : (w == 2) ? 128 : 160;
    const u16* g0 = qkv + ((size_t)(n * 64 + l) * BSZ_ + b) * NQKV_ + hh * 192 + goff;

    u16x8 pre[8];
    if (w < 2) {
        #pragma unroll
        for (int j = 0; j < 8; j++) pre[j] = *(const u16x8*)(g0 + j * 8);
    } else {
        #pragma unroll
        for (int j = 0; j < 4; j++) pre[j] = *(const u16x8*)(g0 + j * 8);
    }

    if (w < 2) {
        float f[64];
        #pragma unroll
        for (int j = 0; j < 8; j++)
            #pragma unroll
            for (int m = 0; m < 8; m++) {
                float x = b2f(pre[j][m]);
                f[j * 8 + m] = x > 0.f ? x + 1.f : __expf(x);
            }
        float s = 0.f;
        #pragma unroll
        for (int i = 0; i < 64; i++) s += f[i];
        float inv = 1.f / (s + 1e-5f);
        u16* dst = (w == 0) ? Q_l : K_l;
        #pragma unroll
        for (int j = 0; j < 8; j++) {
            u16x8 o;
            #pragma unroll
            for (int m = 0; m < 8; m++) o[m] = f2b(f[j * 8 + m] * inv);
            *(u16x8*)((char*)dst + TI(l, j * 8)) = o;
            if (w == 1) {
                #pragma unroll
                for (int m = 0; m < 8; m++)
                    *(u16*)((char*)Kt_l + TI(j * 8 + m, l)) = o[m];
            }
        }
    } else {
        int e0 = (w == 2) ? 0 : 32;
        #pragma unroll
        for (int j = 0; j < 4; j++)
            #pragma unroll
            for (int m = 0; m < 8; m++)
                *(u16*)((char*)Vt_l + TI(e0 + j * 8 + m, l)) = pre[j][m];
    }
    __syncthreads();

    f32x4 aS[4] = {};
    bf16x8 aK[2];
    #pragma unroll
    for (int ks = 0; ks < 2; ks++)
        aK[ks] = *(const bf16x8*)((const char*)K_l + TI(w * 16 + fr, ks * 32 + fq * 8));
    #pragma unroll
    for (int jt = 0; jt < 4; jt++)
        #pragma unroll
        for (int ks = 0; ks < 2; ks++) {
            bf16x8 bq = *(const bf16x8*)((const char*)Q_l + TI(jt * 16 + fr, ks * 32 + fq * 8));
            aS[jt] = __builtin_amdgcn_mfma_f32_16x16x32_bf16(aK[ks], bq, aS[jt], 0, 0, 0);
        }
    #pragma unroll
    for (int jt = 0; jt < 4; jt++) {
        int t = jt * 16 + fr;
        int s0 = w * 16 + fq * 4;
        u16 e0 = (s0 + 0 <= t) ? f2b(aS[jt][0]) : (u16)0;
        u16 e1 = (s0 + 1 <= t) ? f2b(aS[jt][1]) : (u16)0;
        u16 e2 = (s0 + 2 <= t) ? f2b(aS[jt][2]) : (u16)0;
        u16 e3 = (s0 + 3 <= t) ? f2b(aS[jt][3]) : (u16)0;
        uint2 pkk;
        pkk.x = (unsigned)e0 | ((unsigned)e1 << 16);
        pkk.y = (unsigned)e2 | ((unsigned)e3 << 16);
        *(uint2*)((char*)P_l + TI(t, s0)) = pkk;
    }
    __syncthreads();

    f32x4 aO[4] = {}, aS2[4] = {};
    bf16x8 ap[2], akt[2];
    #pragma unroll
    for (int ks = 0; ks < 2; ks++) {
        ap[ks]  = *(const bf16x8*)((const char*)P_l  + TI(w * 16 + fr, ks * 32 + fq * 8));
        akt[ks] = *(const bf16x8*)((const char*)Kt_l + TI(w * 16 + fr, ks * 32 + fq * 8));
    }
    #pragma unroll
    for (int jt = 0; jt < 4; jt++) {
        #pragma unroll
        for (int ks = 0; ks < 2; ks++) {
            bf16x8 bv = *(const bf16x8*)((const char*)Vt_l + TI(jt * 16 + fr, ks * 32 + fq * 8));
            aO[jt]  = __builtin_amdgcn_mfma_f32_16x16x32_bf16(ap[ks],  bv, aO[jt],  0, 0, 0);
            aS2[jt] = __builtin_amdgcn_mfma_f32_16x16x32_bf16(akt[ks], bv, aS2[jt], 0, 0, 0);
        }
    }
    __syncthreads();

    u16* Sg = Sbuf + ((size_t)bh * 32 + n) * 4096;
    #pragma unroll
    for (int jt = 0; jt < 4; jt++)
        #pragma unroll
        for (int r = 0; r < 4; r++) {
            int rr = w * 16 + fq * 4 + r, cc = jt * 16 + fr;
            *(u16*)((char*)P_l + TI(rr, cc)) = f2b(aO[jt][r]);   // rr=t, cc=e
            Sg[rr * 64 + cc] = f2b(aS2[jt][r]);                  // rr=d, cc=e
        }
    __syncthreads();

    {
        int t = tid >> 2, seg = tid & 3;
        u16x8 o1 = *(const u16x8*)((const char*)P_l + TI(t, seg * 16));
        u16x8 o2 = *(const u16x8*)((const char*)P_l + TI(t, seg * 16 + 8));
        u16* gd = obf + ((size_t)(n * 64 + t) * BSZ_ + b) * NOUT_ + hh * 64 + seg * 16;
        *(u16x8*)(gd) = o1;
        *(u16x8*)(gd + 8) = o2;
    }
}

// ---------------- scanB: exclusive prefix over chunks (in-place bf16) ----------------
__global__ __launch_bounds__(256) void scanB(
        u16* __restrict__ Sbuf, const float* __restrict__ state, float* __restrict__ wfin)
{
    const int blk = blockIdx.x;
    const int bh = blk >> 2;
    const int e0 = (blk & 3) * 1024 + threadIdx.x * 4;
    float4 acc = *(const float4*)(state + (size_t)bh * 4096 + e0);
    u16* Sp = Sbuf + (size_t)bh * 32 * 4096 + e0;
    #pragma unroll
    for (int nn = 0; nn < 32; nn++) {
        u16x4 s = *(const u16x4*)(Sp + nn * 4096);
        u16x4 p;
        p[0] = f2b(acc.x); p[1] = f2b(acc.y); p[2] = f2b(acc.z); p[3] = f2b(acc.w);
        *(u16x4*)(Sp + nn * 4096) = p;
        acc.x += b2f(s[0]); acc.y += b2f(s[1]);
        acc.z += b2f(s[2]); acc.w += b2f(s[3]);
    }
    *(float4*)(wfin + (size_t)bh * 4096 + e0) = acc;
}

// ---------------- scanC: O += Q·W_prefix (grid 4096 = n*128 + bh) ----------------
__global__ __launch_bounds__(256) void scanC(
        const u16* __restrict__ qkv, const u16* __restrict__ Sbuf, u16* __restrict__ obf)
{
    __shared__ u16 Q_l[4096], W_l[4096];

    const int blk = blockIdx.x;
    const int bh = blk & 127, n = blk >> 7;
    const int b = bh >> 4, hh = bh & 15;
    const int tid = threadIdx.x;
    const int w = tid >> 6, l = tid & 63;
    const int fr = l & 15, fq = l >> 4;

    const u16* g0 = qkv + ((size_t)(n * 64 + l) * BSZ_ + b) * NQKV_ + hh * 192;
    u16x8 pre[8];
    if (w == 0) {
        #pragma unroll
        for (int j = 0; j < 8; j++) pre[j] = *(const u16x8*)(g0 + j * 8);
    }

    const u16* Wp = Sbuf + ((size_t)bh * 32 + n) * 4096;
    #pragma unroll
    for (int k2 = 0; k2 < 4; k2++) {
        int g = tid * 4 + k2 * 1024;
        u16x4 s = *(const u16x4*)(Wp + g);
        int d = g >> 6, e = g & 63;
        #pragma unroll
        for (int i2 = 0; i2 < 4; i2++)
            *(u16*)((char*)W_l + TI(e + i2, d)) = s[i2];
    }

    if (w == 0) {
        float f[64];
        #pragma unroll
        for (int j = 0; j < 8; j++)
            #pragma unroll
            for (int m = 0; m < 8; m++) {
                float x = b2f(pre[j][m]);
                f[j * 8 + m] = x > 0.f ? x + 1.f : __expf(x);
            }
        float s = 0.f;
        #pragma unroll
        for (int i = 0; i < 64; i++) s += f[i];
        float inv = 1.f / (s + 1e-5f);
        #pragma unroll
        for (int j = 0; j < 8; j++) {
            u16x8 o;
            #pragma unroll
            for (int m = 0; m < 8; m++) o[m] = f2b(f[j * 8 + m] * inv);
            *(u16x8*)((char*)Q_l + TI(l, j * 8)) = o;
        }
    }
    __syncthreads();

    f32x4 aO[4] = {};
    bf16x8 aq[2];
    #pragma unroll
    for (int ks = 0; ks < 2; ks++)
        aq[ks] = *(const bf16x8*)((const char*)Q_l + TI(w * 16 + fr, ks * 32 + fq * 8));
    #pragma unroll
    for (int jt = 0; jt < 4; jt++)
        #pragma unroll
        for (int ks = 0; ks < 2; ks++) {
            bf16x8 bw = *(const bf16x8*)((const char*)W_l + TI(jt * 16 + fr, ks * 32 + fq * 8));
            aO[jt] = __builtin_amdgcn_mfma_f32_16x16x32_bf16(aq[ks], bw, aO[jt], 0, 0, 0);
        }
    __syncthreads();

    #pragma unroll
    for (int jt = 0; jt < 4; jt++)
        #pragma unroll
        for (int r = 0; r < 4; r++)
            *(u16*)((char*)W_l + TI(w * 16 + fq * 4 + r, jt * 16 + fr)) = f2b(aO[jt][r]);
    __syncthreads();

    {
        int t = tid >> 2, seg = tid & 3;
        u16* gd = obf + ((size_t)(n * 64 + t) * BSZ_ + b) * NOUT_ + hh * 64 + seg * 16;
        u16x8 a1 = *(const u16x8*)((const char*)W_l + TI(t, seg * 16));
        u16x8 a2 = *(const u16x8*)((const char*)W_l + TI(t, seg * 16 + 8));
        u16x8 g1 = *(const u16x8*)(gd);
        u16x8 g2 = *(const u16x8*)(gd + 8);
        u16x8 r1, r2;
        #pragma unroll
        for (int m = 0; m < 8; m++) {
            r1[m] = f2b(b2f(a1[m]) + b2f(g1[m]));
            r2[m] = f2b(b2f(a2[m]) + b2f(g2[m]));
        }
        *(u16x8*)(gd) = r1;
        *(u16x8*)(gd + 8) = r2;
    }
}

extern "C" void kernel_launch(void* const* d_in, const int* in_sizes, int n_in,
                              void* d_out, int out_size, void* d_ws, size_t ws_size,
                              hipStream_t stream) {
    const float* x     = (const float*)d_in[0];
    const float* state = (const float*)d_in[1];
    const float* wqkv  = (const float*)d_in[2];
    const float* wout  = (const float*)d_in[3];
    const float* gamma = (const float*)d_in[4];
    const float* beta  = (const float*)d_in[5];

    float* out0 = (float*)d_out;
    float* wfin = (float*)d_out + (size_t)MROWS_ * IND_;

    char* ws = (char*)d_ws;
    u16* qkv_bf = (u16*)ws;                                   // 96 MiB
    u16* h_bf   = (u16*)(ws + 100663296);                     // 32 MiB (o_bf reuse)
    u16* o_bf   = h_bf;
    u16* wq_bf  = (u16*)(ws + 134217728);                     // 6 MiB
    u16* wo_bf  = (u16*)(ws + 140509184);                     // 2 MiB
    u16* S_bf   = (u16*)(ws + 142606336);                     // 32 MiB (S / prefix)

    cast_weights<<<4096, 256, 0, stream>>>(wqkv, wout, wq_bf, wo_bf);
    ln_kernel<<<MROWS_, 256, 0, stream>>>(x, gamma, beta, h_bf);
    dim3 g1(MROWS_ / 256, NQKV_ / 256);   // 64 x 12 = 768 blocks
    gemm256<0><<<g1, 512, 0, stream>>>(h_bf, wq_bf, qkv_bf, nullptr, nullptr, MROWS_, NQKV_, IND_);
    scanA<<<4096, 256, 0, stream>>>(qkv_bf, o_bf, S_bf);
    scanB<<<512, 256, 0, stream>>>(S_bf, state, wfin);
    scanC<<<4096, 256, 0, stream>>>(qkv_bf, S_bf, o_bf);
    dim3 g2(MROWS_ / 256, NOUT_ / 256);   // 64 x 4 = 256 blocks
    gemm256<1><<<g2, 512, 0, stream>>>(o_bf, wo_bf, nullptr, out0, x, MROWS_, NOUT_, IND_);
}

// Round 9
// 250.708 us; speedup vs baseline: 1.5048x; 1.0528x over previous
//
#include <hip/hip_runtime.h>

typedef unsigned short u16;
typedef __attribute__((ext_vector_type(4))) unsigned short u16x4;
typedef __attribute__((ext_vector_type(8))) unsigned short u16x8;
typedef __attribute__((ext_vector_type(8))) __bf16 bf16x8;
typedef __attribute__((ext_vector_type(4))) float f32x4;

#define SLEN_ 2048
#define BSZ_ 8
#define NH_ 16
#define DH_ 64
#define IND_ 1024
#define MROWS_ (SLEN_*BSZ_)   // 16384
#define NQKV_ (NH_*3*DH_)     // 3072
#define NOUT_ (NH_*DH_)       // 1024
#define NT_ 16                // K-tiles of 64 (K=1024)

__device__ __forceinline__ float b2f(u16 u) {
    return __uint_as_float(((unsigned)u) << 16);
}
__device__ __forceinline__ u16 f2b(float f) {
    unsigned u = __float_as_uint(f);
    u = u + 0x7FFFu + ((u >> 16) & 1u);   // RNE
    return (u16)(u >> 16);
}

#define GLOAD_LDS16(g, l) __builtin_amdgcn_global_load_lds( \
    (const __attribute__((address_space(1))) unsigned int*)(g), \
    (__attribute__((address_space(3))) unsigned int*)(l), 16, 0, 0)

// swizzled LDS byte offset for [64][64] bf16 tiles (row stride 128 B)
#define TI(r, c) ((((r) << 7) + ((c) << 1)) ^ (((r) & 7) << 4))

// ---------------- cast fp32 weights -> bf16 ----------------
__global__ __launch_bounds__(256) void cast_weights(
        const float* __restrict__ wq, const float* __restrict__ wo,
        u16* __restrict__ wqb, u16* __restrict__ wob)
{
    int i = blockIdx.x * 256 + threadIdx.x;
    const int NQ4 = NQKV_ * IND_ / 4;
    float4 v;
    u16* dst;
    if (i < NQ4) { v = ((const float4*)wq)[i]; dst = wqb + (size_t)i * 4; }
    else { int j = i - NQ4; v = ((const float4*)wo)[j]; dst = wob + (size_t)j * 4; }
    u16x4 o;
    o[0] = f2b(v.x); o[1] = f2b(v.y); o[2] = f2b(v.z); o[3] = f2b(v.w);
    *(u16x4*)dst = o;
}

// ---------------- LayerNorm -> bf16 ----------------
__global__ __launch_bounds__(256) void ln_kernel(
        const float* __restrict__ x, const float* __restrict__ g,
        const float* __restrict__ bt, u16* __restrict__ h)
{
    int row = blockIdx.x, tid = threadIdx.x;
    const float4 v = ((const float4*)(x + (size_t)row * IND_))[tid];
    float s  = v.x + v.y + v.z + v.w;
    float s2 = v.x*v.x + v.y*v.y + v.z*v.z + v.w*v.w;
    #pragma unroll
    for (int m = 1; m < 64; m <<= 1) { s += __shfl_xor(s, m); s2 += __shfl_xor(s2, m); }
    __shared__ float sh[8];
    int w = tid >> 6, l = tid & 63;
    if (l == 0) { sh[w] = s; sh[4 + w] = s2; }
    __syncthreads();
    s  = sh[0] + sh[1] + sh[2] + sh[3];
    s2 = sh[4] + sh[5] + sh[6] + sh[7];
    float mu   = s * (1.f / IND_);
    float var  = s2 * (1.f / IND_) - mu * mu;
    float rstd = rsqrtf(var + 1e-5f);
    float4 gg = ((const float4*)g)[tid];
    float4 bb = ((const float4*)bt)[tid];
    u16x4 o;
    o[0] = f2b((v.x - mu) * rstd * gg.x + bb.x);
    o[1] = f2b((v.y - mu) * rstd * gg.y + bb.y);
    o[2] = f2b((v.z - mu) * rstd * gg.z + bb.z);
    o[3] = f2b((v.w - mu) * rstd * gg.w + bb.w);
    ((u16x4*)(h + (size_t)row * IND_))[tid] = o;
}

// ---------------- 256x256 bf16 GEMM, C[M,N] = A[M,K]*B[N,K]^T, BK=64 ----------------
// (round-5 version: best measured 114.5us, MfmaUtil 37%, 0 conflicts.
//  Locality XCD map + ks-half lookahead pipeline.)
template<int MODE>
__global__ __launch_bounds__(512, 2) void gemm256(
        const u16* __restrict__ A, const u16* __restrict__ Bm,
        u16* __restrict__ Cb, float* __restrict__ Cf, const float* __restrict__ X,
        int M, int N, int K)
{
    __shared__ char smem[131072];   // [buf][A 32KB | B 32KB]

    const int tid = threadIdx.x;
    const int w = tid >> 6, l = tid & 63;
    const int wmi = w >> 2, wni = w & 3;
    const int fr = l & 15, fq = l >> 4;

    const int h = blockIdx.y * gridDim.x + blockIdx.x;
    const int xcd = h & 7, i = h >> 3;
    const int bm = xcd * 8 + (i & 7);
    const int bn = i >> 3;

    const int sr = l >> 3;
    const int sc = ((l & 7) ^ sr) * 8;
    const u16* ga = A  + (size_t)(bm * 256 + w * 8 + sr) * K + sc;
    const u16* gb = Bm + (size_t)(bn * 256 + w * 8 + sr) * K + sc;
    char* lA = smem + w * 1024;
    char* lB = smem + 32768 + w * 1024;
    const size_t K64 = (size_t)K * 64;

#define STAGE(t, bufb) { \
    const u16* gat = ga + (t) * 64; const u16* gbt = gb + (t) * 64; \
    char* la = lA + (bufb) * 65536; char* lb = lB + (bufb) * 65536; \
    GLOAD_LDS16(gat,            la);            \
    GLOAD_LDS16(gat + K64,      la + 8192);     \
    GLOAD_LDS16(gat + 2 * K64,  la + 16384);    \
    GLOAD_LDS16(gat + 3 * K64,  la + 24576);    \
    GLOAD_LDS16(gbt,            lb);            \
    GLOAD_LDS16(gbt + K64,      lb + 8192);     \
    GLOAD_LDS16(gbt + 2 * K64,  lb + 16384);    \
    GLOAD_LDS16(gbt + 3 * K64,  lb + 24576);    \
}

    const int cswz = (fr & 7) << 4;
    const int c0 = (fq * 16) ^ cswz;
    const int c1 = (64 + fq * 16) ^ cswz;
    const char* rdA = smem + (wmi * 128 + fr) * 128;
    const char* rdB = smem + 32768 + (wni * 64 + fr) * 128;

#define RD_FRAGS(dstA, dstB, base_off, cc) { \
    const char* bA_ = rdA + (base_off); const char* bB_ = rdB + (base_off); \
    _Pragma("unroll") for (int m_ = 0; m_ < 8; m_++) \
        dstA[m_] = *(const bf16x8*)(bA_ + m_ * 2048 + (cc)); \
    _Pragma("unroll") for (int n_ = 0; n_ < 4; n_++) \
        dstB[n_] = *(const bf16x8*)(bB_ + n_ * 2048 + (cc)); \
}

#define MFMA32(srcA, srcB) { \
    _Pragma("unroll") for (int m_ = 0; m_ < 8; m_++) \
        _Pragma("unroll") for (int n_ = 0; n_ < 4; n_++) \
            acc[m_][n_] = __builtin_amdgcn_mfma_f32_16x16x32_bf16(srcA[m_], srcB[n_], acc[m_][n_], 0, 0, 0); \
}

    f32x4 acc[8][4] = {};
    bf16x8 fsA_A[8], fsA_B[4];
    bf16x8 fsB_A[8], fsB_B[4];

    STAGE(0, 0);
    STAGE(1, 1);
    asm volatile("s_waitcnt vmcnt(8)" ::: "memory");
    __builtin_amdgcn_s_barrier();
    RD_FRAGS(fsA_A, fsA_B, 0, c0);
    asm volatile("s_waitcnt lgkmcnt(0)" ::: "memory");
    __builtin_amdgcn_sched_barrier(0);

    #pragma unroll 1
    for (int t = 0; t < NT_; t++) {
        const int cur = (t & 1) * 65536;
        const int nxt = ((t + 1) & 1) * 65536;
        RD_FRAGS(fsB_A, fsB_B, cur, c1);
        __builtin_amdgcn_s_setprio(1);
        MFMA32(fsA_A, fsA_B);
        __builtin_amdgcn_s_setprio(0);
        asm volatile("s_waitcnt lgkmcnt(0)" ::: "memory");
        __builtin_amdgcn_sched_barrier(0);
        __builtin_amdgcn_s_barrier();
        if (t + 2 < NT_) STAGE(t + 2, t & 1);
        if (t < NT_ - 2) asm volatile("s_waitcnt vmcnt(8)" ::: "memory");
        else             asm volatile("s_waitcnt vmcnt(0)" ::: "memory");
        __builtin_amdgcn_s_barrier();
        if (t < NT_ - 1) RD_FRAGS(fsA_A, fsA_B, nxt, c0);
        __builtin_amdgcn_s_setprio(1);
        MFMA32(fsB_A, fsB_B);
        __builtin_amdgcn_s_setprio(0);
        asm volatile("s_waitcnt lgkmcnt(0)" ::: "memory");
        __builtin_amdgcn_sched_barrier(0);
        __builtin_amdgcn_s_barrier();
    }
#undef STAGE
#undef RD_FRAGS
#undef MFMA32

    #pragma unroll
    for (int m = 0; m < 8; m++)
        #pragma unroll
        for (int r = 0; r < 4; r++) {
            int row = bm * 256 + wmi * 128 + m * 16 + fq * 4 + r;
            #pragma unroll
            for (int n = 0; n < 4; n++) {
                int col = bn * 256 + wni * 64 + n * 16 + fr;
                float vv = acc[m][n][r];
                if (MODE == 0) {
                    Cb[(size_t)row * N + col] = f2b(vv);
                } else {
                    size_t idx = (size_t)row * N + col;
                    Cf[idx] = vv + X[idx];
                }
            }
        }
}

// ---------------- scanS: S_c = K^T V per chunk (grid 4096 = n*128 + bh) ----------------
__global__ __launch_bounds__(256) void scanS(
        const u16* __restrict__ qkv, u16* __restrict__ Sbuf)
{
    __shared__ u16 Kt_l[4096], Vt_l[4096];

    const int blk = blockIdx.x;
    const int bh = blk & 127, n = blk >> 7;
    const int b = bh >> 4, hh = bh & 15;
    const int tid = threadIdx.x;
    const int w = tid >> 6, l = tid & 63;
    const int fr = l & 15, fq = l >> 4;

    // staging: w0 = k rows (elu+norm, transposed), w1/w2 = v halves (transposed)
    if (w == 0) {
        const u16* g0 = qkv + ((size_t)(n * 64 + l) * BSZ_ + b) * NQKV_ + hh * 192 + 64;
        u16x8 pre[8];
        #pragma unroll
        for (int j = 0; j < 8; j++) pre[j] = *(const u16x8*)(g0 + j * 8);
        float f[64];
        #pragma unroll
        for (int j = 0; j < 8; j++)
            #pragma unroll
            for (int m = 0; m < 8; m++) {
                float x = b2f(pre[j][m]);
                f[j * 8 + m] = x > 0.f ? x + 1.f : __expf(x);
            }
        float s = 0.f;
        #pragma unroll
        for (int i = 0; i < 64; i++) s += f[i];
        float inv = 1.f / (s + 1e-5f);
        #pragma unroll
        for (int j = 0; j < 8; j++)
            #pragma unroll
            for (int m = 0; m < 8; m++)
                *(u16*)((char*)Kt_l + TI(j * 8 + m, l)) = f2b(f[j * 8 + m] * inv);
    } else if (w <= 2) {
        const u16* g0 = qkv + ((size_t)(n * 64 + l) * BSZ_ + b) * NQKV_ + hh * 192 + 128 + (w - 1) * 32;
        int e0 = (w - 1) * 32;
        u16x8 pre[4];
        #pragma unroll
        for (int j = 0; j < 4; j++) pre[j] = *(const u16x8*)(g0 + j * 8);
        #pragma unroll
        for (int j = 0; j < 4; j++)
            #pragma unroll
            for (int m = 0; m < 8; m++)
                *(u16*)((char*)Vt_l + TI(e0 + j * 8 + m, l)) = pre[j][m];
    }
    __syncthreads();

    // S[d][e] = Kt[d] . Vt[e]
    f32x4 aS2[4] = {};
    bf16x8 akt[2];
    #pragma unroll
    for (int ks = 0; ks < 2; ks++)
        akt[ks] = *(const bf16x8*)((const char*)Kt_l + TI(w * 16 + fr, ks * 32 + fq * 8));
    #pragma unroll
    for (int jt = 0; jt < 4; jt++)
        #pragma unroll
        for (int ks = 0; ks < 2; ks++) {
            bf16x8 bv = *(const bf16x8*)((const char*)Vt_l + TI(jt * 16 + fr, ks * 32 + fq * 8));
            aS2[jt] = __builtin_amdgcn_mfma_f32_16x16x32_bf16(akt[ks], bv, aS2[jt], 0, 0, 0);
        }

    u16* Sg = Sbuf + ((size_t)bh * 32 + n) * 4096;
    #pragma unroll
    for (int jt = 0; jt < 4; jt++)
        #pragma unroll
        for (int r = 0; r < 4; r++)
            Sg[(w * 16 + fq * 4 + r) * 64 + jt * 16 + fr] = f2b(aS2[jt][r]);
}

// ---------------- scanB: exclusive prefix over chunks (in-place bf16) ----------------
__global__ __launch_bounds__(256) void scanB(
        u16* __restrict__ Sbuf, const float* __restrict__ state, float* __restrict__ wfin)
{
    const int blk = blockIdx.x;
    const int bh = blk >> 2;
    const int e0 = (blk & 3) * 1024 + threadIdx.x * 4;
    float4 acc = *(const float4*)(state + (size_t)bh * 4096 + e0);
    u16* Sp = Sbuf + (size_t)bh * 32 * 4096 + e0;
    #pragma unroll
    for (int nn = 0; nn < 32; nn++) {
        u16x4 s = *(const u16x4*)(Sp + nn * 4096);
        u16x4 p;
        p[0] = f2b(acc.x); p[1] = f2b(acc.y); p[2] = f2b(acc.z); p[3] = f2b(acc.w);
        *(u16x4*)(Sp + nn * 4096) = p;
        acc.x += b2f(s[0]); acc.y += b2f(s[1]);
        acc.z += b2f(s[2]); acc.w += b2f(s[3]);
    }
    *(float4*)(wfin + (size_t)bh * 4096 + e0) = acc;
}

// ---------------- scanO: O = tril(K·Q^T)·V + Q·W_prefix (grid 4096) ----------------
// Fuses old scanA's O_intra and scanC's O_cross in ONE f32 accumulator; plain
// coalesced store (no RMW, one fewer bf16 rounding of O).
__global__ __launch_bounds__(256) void scanO(
        const u16* __restrict__ qkv, const u16* __restrict__ Sbuf, u16* __restrict__ obf)
{
    __shared__ u16 Q_l[4096], K_l[4096], Vt_l[4096], P_l[4096], W_l[4096];

    const int blk = blockIdx.x;
    const int bh = blk & 127, n = blk >> 7;
    const int b = bh >> 4, hh = bh & 15;
    const int tid = threadIdx.x;
    const int w = tid >> 6, l = tid & 63;
    const int fr = l & 15, fq = l >> 4;

    // issue q/k/v loads first (w0=q, w1=k, w2/w3=v halves)
    int goff = (w == 0) ? 0 : (w == 1) ? 64 : (w == 2) ? 128 : 160;
    const u16* g0 = qkv + ((size_t)(n * 64 + l) * BSZ_ + b) * NQKV_ + hh * 192 + goff;
    u16x8 pre[8];
    if (w < 2) {
        #pragma unroll
        for (int j = 0; j < 8; j++) pre[j] = *(const u16x8*)(g0 + j * 8);
    } else {
        #pragma unroll
        for (int j = 0; j < 4; j++) pre[j] = *(const u16x8*)(g0 + j * 8);
    }

    // W_l fill from bf16 prefix [d][e] -> swizzled [e][d] (all threads; overlaps loads)
    const u16* Wp = Sbuf + ((size_t)bh * 32 + n) * 4096;
    #pragma unroll
    for (int k2 = 0; k2 < 4; k2++) {
        int g = tid * 4 + k2 * 1024;
        u16x4 s = *(const u16x4*)(Wp + g);
        int d = g >> 6, e = g & 63;
        #pragma unroll
        for (int i2 = 0; i2 < 4; i2++)
            *(u16*)((char*)W_l + TI(e + i2, d)) = s[i2];
    }

    // process staged regs -> LDS
    if (w < 2) {
        float f[64];
        #pragma unroll
        for (int j = 0; j < 8; j++)
            #pragma unroll
            for (int m = 0; m < 8; m++) {
                float x = b2f(pre[j][m]);
                f[j * 8 + m] = x > 0.f ? x + 1.f : __expf(x);
            }
        float s = 0.f;
        #pragma unroll
        for (int i = 0; i < 64; i++) s += f[i];
        float inv = 1.f / (s + 1e-5f);
        u16* dst = (w == 0) ? Q_l : K_l;
        #pragma unroll
        for (int j = 0; j < 8; j++) {
            u16x8 o;
            #pragma unroll
            for (int m = 0; m < 8; m++) o[m] = f2b(f[j * 8 + m] * inv);
            *(u16x8*)((char*)dst + TI(l, j * 8)) = o;
        }
    } else {
        int e0 = (w == 2) ? 0 : 32;
        #pragma unroll
        for (int j = 0; j < 4; j++)
            #pragma unroll
            for (int m = 0; m < 8; m++)
                *(u16*)((char*)Vt_l + TI(e0 + j * 8 + m, l)) = pre[j][m];
    }
    __syncthreads();

    // St = K·Q^T (out rows s = w*16.., cols t); masked P[t][s] -> P_l
    f32x4 aS[4] = {};
    bf16x8 aK[2];
    #pragma unroll
    for (int ks = 0; ks < 2; ks++)
        aK[ks] = *(const bf16x8*)((const char*)K_l + TI(w * 16 + fr, ks * 32 + fq * 8));
    #pragma unroll
    for (int jt = 0; jt < 4; jt++)
        #pragma unroll
        for (int ks = 0; ks < 2; ks++) {
            bf16x8 bq = *(const bf16x8*)((const char*)Q_l + TI(jt * 16 + fr, ks * 32 + fq * 8));
            aS[jt] = __builtin_amdgcn_mfma_f32_16x16x32_bf16(aK[ks], bq, aS[jt], 0, 0, 0);
        }
    #pragma unroll
    for (int jt = 0; jt < 4; jt++) {
        int t = jt * 16 + fr;
        int s0 = w * 16 + fq * 4;
        u16 e0 = (s0 + 0 <= t) ? f2b(aS[jt][0]) : (u16)0;
        u16 e1 = (s0 + 1 <= t) ? f2b(aS[jt][1]) : (u16)0;
        u16 e2 = (s0 + 2 <= t) ? f2b(aS[jt][2]) : (u16)0;
        u16 e3 = (s0 + 3 <= t) ? f2b(aS[jt][3]) : (u16)0;
        uint2 pkk;
        pkk.x = (unsigned)e0 | ((unsigned)e1 << 16);
        pkk.y = (unsigned)e2 | ((unsigned)e3 << 16);
        *(uint2*)((char*)P_l + TI(t, s0)) = pkk;
    }
    __syncthreads();

    // O = P·V + Q·W_prefix (rows t = w*16..)
    f32x4 aO[4] = {};
    bf16x8 ap[2], aq2[2];
    #pragma unroll
    for (int ks = 0; ks < 2; ks++) {
        ap[ks]  = *(const bf16x8*)((const char*)P_l + TI(w * 16 + fr, ks * 32 + fq * 8));
        aq2[ks] = *(const bf16x8*)((const char*)Q_l + TI(w * 16 + fr, ks * 32 + fq * 8));
    }
    #pragma unroll
    for (int jt = 0; jt < 4; jt++) {
        #pragma unroll
        for (int ks = 0; ks < 2; ks++) {
            bf16x8 bv = *(const bf16x8*)((const char*)Vt_l + TI(jt * 16 + fr, ks * 32 + fq * 8));
            aO[jt] = __builtin_amdgcn_mfma_f32_16x16x32_bf16(ap[ks], bv, aO[jt], 0, 0, 0);
        }
        #pragma unroll
        for (int ks = 0; ks < 2; ks++) {
            bf16x8 bw = *(const bf16x8*)((const char*)W_l + TI(jt * 16 + fr, ks * 32 + fq * 8));
            aO[jt] = __builtin_amdgcn_mfma_f32_16x16x32_bf16(aq2[ks], bw, aO[jt], 0, 0, 0);
        }
    }
    __syncthreads();

    // stage O into P_l (rows t, cols e)
    #pragma unroll
    for (int jt = 0; jt < 4; jt++)
        #pragma unroll
        for (int r = 0; r < 4; r++)
            *(u16*)((char*)P_l + TI(w * 16 + fq * 4 + r, jt * 16 + fr)) = f2b(aO[jt][r]);
    __syncthreads();

    // coalesced O global write
    {
        int t = tid >> 2, seg = tid & 3;
        u16x8 o1 = *(const u16x8*)((const char*)P_l + TI(t, seg * 16));
        u16x8 o2 = *(const u16x8*)((const char*)P_l + TI(t, seg * 16 + 8));
        u16* gd = obf + ((size_t)(n * 64 + t) * BSZ_ + b) * NOUT_ + hh * 64 + seg * 16;
        *(u16x8*)(gd) = o1;
        *(u16x8*)(gd + 8) = o2;
    }
}

extern "C" void kernel_launch(void* const* d_in, const int* in_sizes, int n_in,
                              void* d_out, int out_size, void* d_ws, size_t ws_size,
                              hipStream_t stream) {
    const float* x     = (const float*)d_in[0];
    const float* state = (const float*)d_in[1];
    const float* wqkv  = (const float*)d_in[2];
    const float* wout  = (const float*)d_in[3];
    const float* gamma = (const float*)d_in[4];
    const float* beta  = (const float*)d_in[5];

    float* out0 = (float*)d_out;
    float* wfin = (float*)d_out + (size_t)MROWS_ * IND_;

    char* ws = (char*)d_ws;
    u16* qkv_bf = (u16*)ws;                                   // 96 MiB
    u16* h_bf   = (u16*)(ws + 100663296);                     // 32 MiB (o_bf reuse)
    u16* o_bf   = h_bf;
    u16* wq_bf  = (u16*)(ws + 134217728);                     // 6 MiB
    u16* wo_bf  = (u16*)(ws + 140509184);                     // 2 MiB
    u16* S_bf   = (u16*)(ws + 142606336);                     // 32 MiB (S / prefix)

    cast_weights<<<4096, 256, 0, stream>>>(wqkv, wout, wq_bf, wo_bf);
    ln_kernel<<<MROWS_, 256, 0, stream>>>(x, gamma, beta, h_bf);
    dim3 g1(MROWS_ / 256, NQKV_ / 256);   // 64 x 12 = 768 blocks
    gemm256<0><<<g1, 512, 0, stream>>>(h_bf, wq_bf, qkv_bf, nullptr, nullptr, MROWS_, NQKV_, IND_);
    scanS<<<4096, 256, 0, stream>>>(qkv_bf, S_bf);
    scanB<<<512, 256, 0, stream>>>(S_bf, state, wfin);
    scanO<<<4096, 256, 0, stream>>>(qkv_bf, S_bf, o_bf);
    dim3 g2(MROWS_ / 256, NOUT_ / 256);   // 64 x 4 = 256 blocks
    gemm256<1><<<g2, 512, 0, stream>>>(o_bf, wo_bf, nullptr, out0, x, MROWS_, NOUT_, IND_);
}